// Round 1
// baseline (376.351 us; speedup 1.0000x reference)
//
#include <hip/hip_runtime.h>

// IPLS partial_fit, n=100 (> BURN_IN) path only.
// Reformulated: all per-component scalars derive from a 65x65 Gram of
// [xc, P_0..31, Wz_0..31] (x-side) and 33x33 Gram of [yc, Cz_0..31] (y-side),
// since xr_i / yr_i stay in the span of those bases under deflation.

#define NF 262144
#define NT 8192
#define NL 32
#define NBX 256          // x-side gram blocks (chunk 1024 = 4 windows)
#define NBY 32           // y-side gram blocks (chunk 256 = 1 window)
#define WIN 256          // floats per LDS window
#define GXS 68           // padded x gram stride (17 groups * 4 rows)
#define GYS 36           // padded y gram stride (9 groups * 4 rows)

#define WS_GX 0
#define WS_GY (68*68)
#define WS_COEF (68*68 + 36*36)

#define OUT_MU_X 0
#define OUT_MU_Y 262144
#define OUT_U    270336
#define OUT_WZ   270368
#define OUT_CZ   8658976
#define OUT_TSS  8921120
#define OUT_BZ   8921152
#define OUT_P    8921184

__device__ __forceinline__ int ldsoff(int row, int c4) {
  // XOR swizzle on the float4-column index; rows are 4-strided across tiles,
  // so swizzle by (row>>2)&7 to spread lanes over all 8 bank groups.
  return row * 256 + ((c4 ^ ((row >> 2) & 7)) << 2);
}

__device__ __forceinline__ float4 ld4(const float* p) { return *(const float4*)p; }
__device__ __forceinline__ void fma4(float4& a, float c, const float4& b) {
  a.x += c * b.x; a.y += c * b.y; a.z += c * b.z; a.w += c * b.w;
}

__global__ __launch_bounds__(256) void gram_kernel(
    const float* __restrict__ x, const float* __restrict__ y,
    const float* __restrict__ mux, const float* __restrict__ muy,
    const float* __restrict__ Wz, const float* __restrict__ Cz,
    const float* __restrict__ P, const int* __restrict__ np,
    float* __restrict__ ws)
{
  __shared__ float lds[68 * 256];
  const int tid = threadIdx.x;
  const int b = blockIdx.x;
  const float n1 = (float)(np[0] + 1);
  const float cmu = n1 / (n1 + 1.0f);   // xc = cmu*(x - mu_x_old)
  float* GX = ws + WS_GX;
  float* GY = ws + WS_GY;

  if (b < NBX) {
    // ---- x-side: rows [xc, P_0..31, Wz_0..31] padded to 68 ----
    int gu = 0, gv = 0; bool active = false;
    if (tid < 153) {
      int t = tid;
      for (int g = 0; g < 17; ++g) {
        int c = 17 - g;
        if (t < c) { gu = g; gv = g + t; active = true; break; }
        t -= c;
      }
    }
    float acc[16];
#pragma unroll
    for (int i = 0; i < 16; ++i) acc[i] = 0.f;

    const int kbase = b * (4 * WIN);
    for (int w = 0; w < 4; ++w) {
      const int wb = kbase + w * WIN;
      // stage 68 rows x 256 floats (coalesced: wave = one row segment)
#pragma unroll
      for (int it = 0; it < 17; ++it) {
        int idx = tid + it * 256;
        int row = idx >> 6;
        int c4 = idx & 63;
        int k = wb + c4 * 4;
        float4 v;
        if (row == 0) {
          float4 xv = ld4(x + k);
          float4 mv = ld4(mux + k);
          v.x = cmu * (xv.x - mv.x); v.y = cmu * (xv.y - mv.y);
          v.z = cmu * (xv.z - mv.z); v.w = cmu * (xv.w - mv.w);
        } else if (row < 33) {
          v = ld4(P + (size_t)(row - 1) * NF + k);
        } else if (row < 65) {
          v = ld4(Wz + (size_t)(row - 33) * NF + k);
        } else {
          v = make_float4(0.f, 0.f, 0.f, 0.f);
        }
        *(float4*)&lds[ldsoff(row, c4)] = v;
      }
      __syncthreads();
      if (active) {
        const int swu = gu & 7, swv = gv & 7;
        const int ub = 4 * gu * 256, vb = 4 * gv * 256;
        for (int c = 0; c < 64; ++c) {
          const int cu = ((c ^ swu) << 2);
          const int cv = ((c ^ swv) << 2);
          float4 av[4], bv[4];
#pragma unroll
          for (int r2 = 0; r2 < 4; ++r2) av[r2] = *(const float4*)&lds[ub + r2 * 256 + cu];
#pragma unroll
          for (int s2 = 0; s2 < 4; ++s2) bv[s2] = *(const float4*)&lds[vb + s2 * 256 + cv];
#pragma unroll
          for (int r2 = 0; r2 < 4; ++r2)
#pragma unroll
            for (int s2 = 0; s2 < 4; ++s2)
              acc[r2 * 4 + s2] += av[r2].x * bv[s2].x + av[r2].y * bv[s2].y +
                                  av[r2].z * bv[s2].z + av[r2].w * bv[s2].w;
        }
      }
      __syncthreads();
    }
    if (active) {
#pragma unroll
      for (int r2 = 0; r2 < 4; ++r2)
        for (int s2 = 0; s2 < 4; ++s2) {
          int uu = 4 * gu + r2, vv = 4 * gv + s2;
          float val = acc[r2 * 4 + s2];
          atomicAdd(&GX[uu * GXS + vv], val);
          if (gu != gv) atomicAdd(&GX[vv * GXS + uu], val);  // diag tiles already cover both orders
        }
    }
  } else {
    // ---- y-side: rows [yc, Cz_0..31] padded to 36 ----
    const int yb = b - NBX;
    int gu = 0, gv = 0; bool active = false;
    if (tid < 45) {
      int t = tid;
      for (int g = 0; g < 9; ++g) {
        int c = 9 - g;
        if (t < c) { gu = g; gv = g + t; active = true; break; }
        t -= c;
      }
    }
    float acc[16];
#pragma unroll
    for (int i = 0; i < 16; ++i) acc[i] = 0.f;
    const int wb = yb * WIN;
#pragma unroll
    for (int it = 0; it < 9; ++it) {
      int idx = tid + it * 256;
      int row = idx >> 6;
      int c4 = idx & 63;
      int k = wb + c4 * 4;
      float4 v;
      if (row == 0) {
        float4 yv = ld4(y + k);
        float4 mv = ld4(muy + k);
        v.x = cmu * (yv.x - mv.x); v.y = cmu * (yv.y - mv.y);
        v.z = cmu * (yv.z - mv.z); v.w = cmu * (yv.w - mv.w);
      } else if (row < 33) {
        v = ld4(Cz + (size_t)(row - 1) * NT + k);
      } else {
        v = make_float4(0.f, 0.f, 0.f, 0.f);
      }
      *(float4*)&lds[ldsoff(row, c4)] = v;
    }
    __syncthreads();
    if (active) {
      const int swu = gu & 7, swv = gv & 7;
      const int ub = 4 * gu * 256, vb = 4 * gv * 256;
      for (int c = 0; c < 64; ++c) {
        const int cu = ((c ^ swu) << 2);
        const int cv = ((c ^ swv) << 2);
        float4 av[4], bv[4];
#pragma unroll
        for (int r2 = 0; r2 < 4; ++r2) av[r2] = *(const float4*)&lds[ub + r2 * 256 + cu];
#pragma unroll
        for (int s2 = 0; s2 < 4; ++s2) bv[s2] = *(const float4*)&lds[vb + s2 * 256 + cv];
#pragma unroll
        for (int r2 = 0; r2 < 4; ++r2)
#pragma unroll
          for (int s2 = 0; s2 < 4; ++s2)
            acc[r2 * 4 + s2] += av[r2].x * bv[s2].x + av[r2].y * bv[s2].y +
                                av[r2].z * bv[s2].z + av[r2].w * bv[s2].w;
      }
#pragma unroll
      for (int r2 = 0; r2 < 4; ++r2)
        for (int s2 = 0; s2 < 4; ++s2) {
          int uu = 4 * gu + r2, vv = 4 * gv + s2;
          float val = acc[r2 * 4 + s2];
          atomicAdd(&GY[uu * GYS + vv], val);
          if (gu != gv) atomicAdd(&GY[vv * GYS + uu], val);
        }
    }
  }
}

// One wave: f64 scalar recurrences for all 32 components.
// Lane l<32 owns p[l]=xr.P_l, w[l]=xr.Wz_l, e[l]=yr.Cz_l; lanes 0..32 own
// the basis coefficients of xr (cx) and yr (cy).
__global__ void solve_kernel(const float* __restrict__ ws,
                             const float* __restrict__ u_in,
                             const float* __restrict__ tss_in,
                             const float* __restrict__ bz_in,
                             float* __restrict__ coef,
                             float* __restrict__ out)
{
  const int l = threadIdx.x;  // 0..63
  const float* GX = ws + WS_GX;
  const float* GY = ws + WS_GY;
  float* AWZ = coef;               // 32 x 33
  float* AP  = coef + 33 * NL;     // 32 x 33 (identity for +P_i folded in)
  float* ACZ = coef + 66 * NL;     // 32 x 33 (identity for +Cz_i folded in)

  double q = (double)GX[0];                       // ||xr||^2
  double r = (double)GY[0];                       // ||yr||^2
  double pj = (l < 32) ? (double)GX[1 + l]  : 0.0;
  double wj = (l < 32) ? (double)GX[33 + l] : 0.0;
  double ej = (l < 32) ? (double)GY[1 + l]  : 0.0;
  double cx = (l == 0) ? 1.0 : 0.0;
  double cy = (l == 0) ? 1.0 : 0.0;

  for (int i = 0; i < NL; ++i) {
    double a  = __shfl(wj, i, 64);   // xr . Wz_i
    double g  = __shfl(ej, i, 64);   // yr . Cz_i
    double pi = __shfl(pj, i, 64);   // xr . P_i
    double s  = (double)GX[(33 + i) * GXS + (33 + i)];  // ||Wz_i||^2
    double h  = (double)GY[(1 + i) * GYS + (1 + i)];    // ||Cz_i||^2
    double u0   = (double)u_in[i];
    double tss0 = (double)tss_in[i];
    double bz0  = (double)bz_in[i];

    double ui = u0, u1 = 0.0, tz = 0.0, tss_ = 0.0, t = 0.0, ncz = 1.0;
#pragma unroll
    for (int pass = 0; pass < 2; ++pass) {
      double num = a + ui * q;
      double den = sqrt(s + 2.0 * ui * a + ui * ui * q) + 1e-7;
      tz = num / den;
      tss_ = tss0 + tz * tz;
      t = tz / sqrt(tss_);
      double ncz2 = h + 2.0 * t * g + t * t * r;
      ncz = sqrt(ncz2);
      ui = (g + t * r) / ncz;
      if (pass == 0) u1 = ui;
    }
    double u2 = ui;
    double bz_new = bz0 + u2 * tz;
    double bb = bz_new / sqrt(tss_);
    double phi = 1.0 - t * t;            // xr' = phi*xr - t*P_i
    double gam = bb * t / ncz;           // yr' = psi*yr - gam*Cz_i
    double psi = 1.0 - gam * t;

    if (l == 0) {
      out[OUT_U + i]   = (float)u2;
      out[OUT_TSS + i] = (float)tss_;
      out[OUT_BZ + i]  = (float)bz_new;
    }
    if (l < 33) {
      AWZ[i * 33 + l] = (float)(u1 * cx);
      AP [i * 33 + l] = (float)(t  * cx) + ((l == 1 + i) ? 1.0f : 0.0f);
      ACZ[i * 33 + l] = (float)(t  * cy) + ((l == 1 + i) ? 1.0f : 0.0f);
    }
    // recurrences (use pre-update a,g,pi)
    q = phi * phi * q - 2.0 * phi * t * pi + t * t * (double)GX[(1 + i) * GXS + (1 + i)];
    r = psi * psi * r - 2.0 * psi * gam * g + gam * gam * h;
    cx *= phi; if (l == 1 + i) cx -= t;
    cy *= psi; if (l == 1 + i) cy -= gam;
    if (l < 32) {
      pj = phi * pj - t * (double)GX[(1 + i) * GXS + (1 + l)];
      wj = phi * wj - t * (double)GX[(1 + i) * GXS + (33 + l)];
      ej = psi * ej - gam * (double)GY[(1 + i) * GYS + (1 + l)];
    }
  }
}

__global__ __launch_bounds__(256) void out_kernel(
    const float* __restrict__ x, const float* __restrict__ y,
    const float* __restrict__ mux, const float* __restrict__ muy,
    const float* __restrict__ Wz, const float* __restrict__ Cz,
    const float* __restrict__ P, const int* __restrict__ np,
    const float* __restrict__ coef, float* __restrict__ out)
{
  const int b = blockIdx.x, tid = threadIdx.x;
  const float n1 = (float)(np[0] + 1);
  const float inv = 1.0f / (n1 + 1.0f);
  const float* AWZ = coef;
  const float* AP  = coef + 33 * NL;
  const float* ACZ = coef + 66 * NL;

  if (b < 256) {
    const int k = (b * 256 + tid) * 4;
    float4 xv = ld4(x + k), mv = ld4(mux + k);
    float4 mn;
    mn.x = (mv.x * n1 + xv.x) * inv; mn.y = (mv.y * n1 + xv.y) * inv;
    mn.z = (mv.z * n1 + xv.z) * inv; mn.w = (mv.w * n1 + xv.w) * inv;
    *(float4*)(out + OUT_MU_X + k) = mn;
    float4 B[33];
    B[0].x = xv.x - mn.x; B[0].y = xv.y - mn.y;
    B[0].z = xv.z - mn.z; B[0].w = xv.w - mn.w;
#pragma unroll
    for (int j = 0; j < 32; ++j) B[1 + j] = ld4(P + (size_t)j * NF + k);
    for (int i = 0; i < NL; ++i) {
      float4 aw = ld4(Wz + (size_t)i * NF + k);
      float4 ap = make_float4(0.f, 0.f, 0.f, 0.f);
#pragma unroll
      for (int j = 0; j < 33; ++j) {
        fma4(aw, AWZ[i * 33 + j], B[j]);
        fma4(ap, AP[i * 33 + j], B[j]);
      }
      *(float4*)(out + OUT_WZ + (size_t)i * NF + k) = aw;
      *(float4*)(out + OUT_P  + (size_t)i * NF + k) = ap;
    }
  } else {
    const int k = ((b - 256) * 256 + tid) * 4;
    float4 yv = ld4(y + k), mv = ld4(muy + k);
    float4 mn;
    mn.x = (mv.x * n1 + yv.x) * inv; mn.y = (mv.y * n1 + yv.y) * inv;
    mn.z = (mv.z * n1 + yv.z) * inv; mn.w = (mv.w * n1 + yv.w) * inv;
    *(float4*)(out + OUT_MU_Y + k) = mn;
    float4 B[33];
    B[0].x = yv.x - mn.x; B[0].y = yv.y - mn.y;
    B[0].z = yv.z - mn.z; B[0].w = yv.w - mn.w;
#pragma unroll
    for (int j = 0; j < 32; ++j) B[1 + j] = ld4(Cz + (size_t)j * NT + k);
    for (int i = 0; i < NL; ++i) {
      float4 ac = make_float4(0.f, 0.f, 0.f, 0.f);
#pragma unroll
      for (int j = 0; j < 33; ++j) fma4(ac, ACZ[i * 33 + j], B[j]);
      *(float4*)(out + OUT_CZ + (size_t)i * NT + k) = ac;
    }
  }
}

extern "C" void kernel_launch(void* const* d_in, const int* in_sizes, int n_in,
                              void* d_out, int out_size, void* d_ws, size_t ws_size,
                              hipStream_t stream) {
  const float* x   = (const float*)d_in[0];
  const float* y   = (const float*)d_in[1];
  const float* mux = (const float*)d_in[2];
  const float* muy = (const float*)d_in[3];
  const float* u   = (const float*)d_in[4];
  const float* Wz  = (const float*)d_in[5];
  const float* Cz  = (const float*)d_in[6];
  const float* tss = (const float*)d_in[7];
  const float* bz  = (const float*)d_in[8];
  const float* P   = (const float*)d_in[9];
  const int*   n   = (const int*)d_in[10];
  float* ws  = (float*)d_ws;
  float* out = (float*)d_out;

  hipMemsetAsync(ws, 0, (size_t)WS_COEF * sizeof(float), stream);
  gram_kernel<<<NBX + NBY, 256, 0, stream>>>(x, y, mux, muy, Wz, Cz, P, n, ws);
  solve_kernel<<<1, 64, 0, stream>>>(ws, u, tss, bz, ws + WS_COEF, out);
  out_kernel<<<256 + 8, 256, 0, stream>>>(x, y, mux, muy, Wz, Cz, P, n, ws + WS_COEF, out);
}

// Round 2
// 343.074 us; speedup vs baseline: 1.0970x; 1.0970x over previous
//
#include <hip/hip_runtime.h>

// IPLS partial_fit (n > BURN_IN). Gram-reformulated:
//   x-side Gram 65x65 of [xc, P_0..31, Wz_0..31], y-side 33x33 of [yc, Cz_0..31]
//   -> 1-wave f64 scalar recurrence solve -> skinny 64x33 output combine.

#define NF 262144
#define NT 8192
#define NL 32
#define GXS 68
#define GYS 36
#define NBX 512          // x-side gram blocks (each: 2 windows of 256 floats)
#define NBY 32           // y-side gram blocks (1 window of 256)
#define NCHUNK 32
#define PART_SZ (68*68)  // 4624

#define WS_PART 0
#define WS_GY   (NCHUNK*PART_SZ)            // 147968
#define WS_GX   (WS_GY + GYS*GYS)           // 149264
#define WS_COEF (WS_GX + PART_SZ)           // 153888  (3*32*33 floats)

#define OUT_MU_X 0
#define OUT_MU_Y 262144
#define OUT_U    270336
#define OUT_WZ   270368
#define OUT_CZ   8658976
#define OUT_TSS  8921120
#define OUT_BZ   8921152
#define OUT_P    8921184

#define LDSW 260   // row stride (floats): 256 + 4 pad to break bank alignment

__device__ __forceinline__ float4 ld4(const float* p) { return *(const float4*)p; }
__device__ __forceinline__ float2 ld2(const float* p) { return *(const float2*)p; }

__global__ __launch_bounds__(320) void gram_kernel(
    const float* __restrict__ x, const float* __restrict__ y,
    const float* __restrict__ mux, const float* __restrict__ muy,
    const float* __restrict__ Wz, const float* __restrict__ Cz,
    const float* __restrict__ P, const int* __restrict__ np,
    float* __restrict__ ws)
{
  __shared__ float lds[66 * LDSW];   // 68.6 KB -> 2 blocks/CU
  const int tid = threadIdx.x;
  const int b = blockIdx.x;
  const float n1 = (float)(np[0] + 1);
  const float cmu = n1 / (n1 + 1.0f);   // xc = cmu*(x - mu_old)

  if (b < NBX) {
    // ---- x-side: 66 rows (xc, P_0..31, Wz_0..31, zero), 6-row groups ----
    // thread t<264: pair p=t>>2 over 11 groups, quarter q=t&3 -> cols q,q+4,...
    const int q = tid & 3;
    int gu = 0, gv = 0; bool active = (tid < 264);
    if (active) {
      int pp = tid >> 2;
      for (int g = 0; g < 11; ++g) {
        int c = 11 - g;
        if (pp < c) { gu = g; gv = g + pp; break; }
        pp -= c;
      }
    }
    float acc[36];
#pragma unroll
    for (int i = 0; i < 36; ++i) acc[i] = 0.f;

    for (int w = 0; w < 2; ++w) {
      const int wb = b * 512 + w * 256;
      // stage 66 rows x 64 float4
      for (int it = 0; it < 14; ++it) {
        int idx = tid + it * 320;
        if (idx < 4224) {
          int row = idx >> 6;
          int c4 = idx & 63;
          int k = wb + c4 * 4;
          float4 v;
          if (row == 0) {
            float4 xv = ld4(x + k), mv = ld4(mux + k);
            v.x = cmu * (xv.x - mv.x); v.y = cmu * (xv.y - mv.y);
            v.z = cmu * (xv.z - mv.z); v.w = cmu * (xv.w - mv.w);
          } else if (row < 33) {
            v = ld4(P + (size_t)(row - 1) * NF + k);
          } else if (row < 65) {
            v = ld4(Wz + (size_t)(row - 33) * NF + k);
          } else {
            v = make_float4(0.f, 0.f, 0.f, 0.f);
          }
          *(float4*)&lds[row * LDSW + c4 * 4] = v;
        }
      }
      __syncthreads();
      if (active) {
        const int ub = 6 * gu * LDSW, vb = 6 * gv * LDSW;
#pragma unroll 4
        for (int cc = 0; cc < 16; ++cc) {
          const int co = (q + cc * 4) * 4;
          float4 av[6], bv[6];
#pragma unroll
          for (int r = 0; r < 6; ++r) av[r] = *(const float4*)&lds[ub + r * LDSW + co];
#pragma unroll
          for (int s = 0; s < 6; ++s) bv[s] = *(const float4*)&lds[vb + s * LDSW + co];
#pragma unroll
          for (int r = 0; r < 6; ++r)
#pragma unroll
            for (int s = 0; s < 6; ++s)
              acc[r * 6 + s] += av[r].x * bv[s].x + av[r].y * bv[s].y +
                                av[r].z * bv[s].z + av[r].w * bv[s].w;
        }
      }
      __syncthreads();
    }
    // combine the 4 quarters (adjacent lanes, never crossing a wave)
#pragma unroll
    for (int e = 0; e < 36; ++e) {
      acc[e] += __shfl_xor(acc[e], 1, 64);
      acc[e] += __shfl_xor(acc[e], 2, 64);
    }
    if (active && q == 0) {
      float* PB = ws + WS_PART + (size_t)(b & (NCHUNK - 1)) * PART_SZ;
#pragma unroll
      for (int r = 0; r < 6; ++r)
#pragma unroll
        for (int s = 0; s < 6; ++s) {
          int u = 6 * gu + r, v = 6 * gv + s;
          if (u < 65 && v < 65) {
            float val = acc[r * 6 + s];
            atomicAdd(&PB[u * GXS + v], val);
            if (gu != gv) atomicAdd(&PB[v * GXS + u], val);
          }
        }
    }
  } else {
    // ---- y-side: 36 rows (yc, Cz_0..31, zeros), 4-row groups, 45 pairs ----
    float* GY = ws + WS_GY;
    const int yb = b - NBX;
    int gu = 0, gv = 0; bool active = (tid < 45);
    if (active) {
      int pp = tid;
      for (int g = 0; g < 9; ++g) {
        int c = 9 - g;
        if (pp < c) { gu = g; gv = g + pp; break; }
        pp -= c;
      }
    }
    float acc[16];
#pragma unroll
    for (int i = 0; i < 16; ++i) acc[i] = 0.f;
    const int wb = yb * 256;
    for (int it = 0; it < 8; ++it) {
      int idx = tid + it * 320;
      if (idx < 2304) {
        int row = idx >> 6;
        int c4 = idx & 63;
        int k = wb + c4 * 4;
        float4 v;
        if (row == 0) {
          float4 yv = ld4(y + k), mv = ld4(muy + k);
          v.x = cmu * (yv.x - mv.x); v.y = cmu * (yv.y - mv.y);
          v.z = cmu * (yv.z - mv.z); v.w = cmu * (yv.w - mv.w);
        } else if (row < 33) {
          v = ld4(Cz + (size_t)(row - 1) * NT + k);
        } else {
          v = make_float4(0.f, 0.f, 0.f, 0.f);
        }
        *(float4*)&lds[row * LDSW + c4 * 4] = v;
      }
    }
    __syncthreads();
    if (active) {
      const int ub = 4 * gu * LDSW, vb = 4 * gv * LDSW;
      for (int c = 0; c < 64; ++c) {
        float4 av[4], bv[4];
#pragma unroll
        for (int r = 0; r < 4; ++r) av[r] = *(const float4*)&lds[ub + r * LDSW + c * 4];
#pragma unroll
        for (int s = 0; s < 4; ++s) bv[s] = *(const float4*)&lds[vb + s * LDSW + c * 4];
#pragma unroll
        for (int r = 0; r < 4; ++r)
#pragma unroll
          for (int s = 0; s < 4; ++s)
            acc[r * 4 + s] += av[r].x * bv[s].x + av[r].y * bv[s].y +
                              av[r].z * bv[s].z + av[r].w * bv[s].w;
      }
#pragma unroll
      for (int r = 0; r < 4; ++r)
#pragma unroll
        for (int s = 0; s < 4; ++s) {
          int u = 4 * gu + r, v = 4 * gv + s;
          if (u < 33 && v < 33) {
            float val = acc[r * 4 + s];
            atomicAdd(&GY[u * GYS + v], val);
            if (gu != gv) atomicAdd(&GY[v * GYS + u], val);
          }
        }
    }
  }
}

__global__ __launch_bounds__(256) void reduce_kernel(float* __restrict__ ws) {
  int e = blockIdx.x * 256 + threadIdx.x;
  if (e < PART_SZ) {
    const float* PB = ws + WS_PART;
    float s = 0.f;
#pragma unroll
    for (int j = 0; j < NCHUNK; ++j) s += PB[(size_t)j * PART_SZ + e];
    ws[WS_GX + e] = s;
  }
}

// One wave: f64 scalar recurrences for all 32 components.
__global__ void solve_kernel(const float* __restrict__ ws,
                             const float* __restrict__ u_in,
                             const float* __restrict__ tss_in,
                             const float* __restrict__ bz_in,
                             float* __restrict__ coef,
                             float* __restrict__ out)
{
  const int l = threadIdx.x;  // 0..63
  const float* GX = ws + WS_GX;
  const float* GY = ws + WS_GY;
  float* AWZ = coef;               // 32 x 33
  float* AP  = coef + 33 * NL;     // 32 x 33 (+P_i identity folded)
  float* ACZ = coef + 66 * NL;     // 32 x 33 (+Cz_i identity folded)

  double q = (double)GX[0];                       // ||xr||^2
  double r = (double)GY[0];                       // ||yr||^2
  double pj = (l < 32) ? (double)GX[1 + l]  : 0.0;
  double wj = (l < 32) ? (double)GX[33 + l] : 0.0;
  double ej = (l < 32) ? (double)GY[1 + l]  : 0.0;
  double cx = (l == 0) ? 1.0 : 0.0;
  double cy = (l == 0) ? 1.0 : 0.0;

  for (int i = 0; i < NL; ++i) {
    double a  = __shfl(wj, i, 64);
    double g  = __shfl(ej, i, 64);
    double pi = __shfl(pj, i, 64);
    double s  = (double)GX[(33 + i) * GXS + (33 + i)];
    double h  = (double)GY[(1 + i) * GYS + (1 + i)];
    double u0   = (double)u_in[i];
    double tss0 = (double)tss_in[i];
    double bz0  = (double)bz_in[i];

    double ui = u0, u1 = 0.0, tz = 0.0, tss_ = 0.0, t = 0.0, ncz = 1.0;
#pragma unroll
    for (int pass = 0; pass < 2; ++pass) {
      double num = a + ui * q;
      double den = sqrt(s + 2.0 * ui * a + ui * ui * q) + 1e-7;
      tz = num / den;
      tss_ = tss0 + tz * tz;
      t = tz / sqrt(tss_);
      double ncz2 = h + 2.0 * t * g + t * t * r;
      ncz = sqrt(ncz2);
      ui = (g + t * r) / ncz;
      if (pass == 0) u1 = ui;
    }
    double u2 = ui;
    double bz_new = bz0 + u2 * tz;
    double bb = bz_new / sqrt(tss_);
    double phi = 1.0 - t * t;            // xr' = phi*xr - t*P_i
    double gam = bb * t / ncz;           // yr' = psi*yr - gam*Cz_i
    double psi = 1.0 - gam * t;

    if (l == 0) {
      out[OUT_U + i]   = (float)u2;
      out[OUT_TSS + i] = (float)tss_;
      out[OUT_BZ + i]  = (float)bz_new;
    }
    if (l < 33) {
      AWZ[i * 33 + l] = (float)(u1 * cx);
      AP [i * 33 + l] = (float)(t  * cx) + ((l == 1 + i) ? 1.0f : 0.0f);
      ACZ[i * 33 + l] = (float)(t  * cy) + ((l == 1 + i) ? 1.0f : 0.0f);
    }
    q = phi * phi * q - 2.0 * phi * t * pi + t * t * (double)GX[(1 + i) * GXS + (1 + i)];
    r = psi * psi * r - 2.0 * psi * gam * g + gam * gam * h;
    cx *= phi; if (l == 1 + i) cx -= t;
    cy *= psi; if (l == 1 + i) cy -= gam;
    if (l < 32) {
      pj = phi * pj - t * (double)GX[(1 + i) * GXS + (1 + l)];
      wj = phi * wj - t * (double)GX[(1 + i) * GXS + (33 + l)];
      ej = psi * ej - gam * (double)GY[(1 + i) * GYS + (1 + l)];
    }
  }
}

__global__ __launch_bounds__(256) void out_kernel(
    const float* __restrict__ x, const float* __restrict__ y,
    const float* __restrict__ mux, const float* __restrict__ muy,
    const float* __restrict__ Wz, const float* __restrict__ Cz,
    const float* __restrict__ P, const int* __restrict__ np,
    const float* __restrict__ coef, float* __restrict__ out)
{
  const int b = blockIdx.x, tid = threadIdx.x;
  const float n1 = (float)(np[0] + 1);
  const float inv = 1.0f / (n1 + 1.0f);
  const float* AWZ = coef;
  const float* AP  = coef + 33 * NL;
  const float* ACZ = coef + 66 * NL;

  if (b < 512) {
    const int k = (b * 256 + tid) * 2;
    float2 xv = ld2(x + k), mv = ld2(mux + k);
    float2 mn;
    mn.x = (mv.x * n1 + xv.x) * inv; mn.y = (mv.y * n1 + xv.y) * inv;
    *(float2*)(out + OUT_MU_X + k) = mn;
    float2 B[33];
    B[0].x = xv.x - mn.x; B[0].y = xv.y - mn.y;
#pragma unroll
    for (int j = 0; j < 32; ++j) B[1 + j] = ld2(P + (size_t)j * NF + k);
    for (int i = 0; i < NL; ++i) {
      float2 aw = ld2(Wz + (size_t)i * NF + k);
      float2 ap = make_float2(0.f, 0.f);
#pragma unroll
      for (int j = 0; j < 33; ++j) {
        float cw = AWZ[i * 33 + j], cp = AP[i * 33 + j];
        aw.x += cw * B[j].x; aw.y += cw * B[j].y;
        ap.x += cp * B[j].x; ap.y += cp * B[j].y;
      }
      *(float2*)(out + OUT_WZ + (size_t)i * NF + k) = aw;
      *(float2*)(out + OUT_P  + (size_t)i * NF + k) = ap;
    }
  } else {
    const int k = ((b - 512) * 256 + tid) * 2;
    float2 yv = ld2(y + k), mv = ld2(muy + k);
    float2 mn;
    mn.x = (mv.x * n1 + yv.x) * inv; mn.y = (mv.y * n1 + yv.y) * inv;
    *(float2*)(out + OUT_MU_Y + k) = mn;
    float2 B[33];
    B[0].x = yv.x - mn.x; B[0].y = yv.y - mn.y;
#pragma unroll
    for (int j = 0; j < 32; ++j) B[1 + j] = ld2(Cz + (size_t)j * NT + k);
    for (int i = 0; i < NL; ++i) {
      float2 ac = make_float2(0.f, 0.f);
#pragma unroll
      for (int j = 0; j < 33; ++j) {
        float cc = ACZ[i * 33 + j];
        ac.x += cc * B[j].x; ac.y += cc * B[j].y;
      }
      *(float2*)(out + OUT_CZ + (size_t)i * NT + k) = ac;
    }
  }
}

extern "C" void kernel_launch(void* const* d_in, const int* in_sizes, int n_in,
                              void* d_out, int out_size, void* d_ws, size_t ws_size,
                              hipStream_t stream) {
  const float* x   = (const float*)d_in[0];
  const float* y   = (const float*)d_in[1];
  const float* mux = (const float*)d_in[2];
  const float* muy = (const float*)d_in[3];
  const float* u   = (const float*)d_in[4];
  const float* Wz  = (const float*)d_in[5];
  const float* Cz  = (const float*)d_in[6];
  const float* tss = (const float*)d_in[7];
  const float* bz  = (const float*)d_in[8];
  const float* P   = (const float*)d_in[9];
  const int*   n   = (const int*)d_in[10];
  float* ws  = (float*)d_ws;
  float* out = (float*)d_out;

  // zero the atomic targets: partial chunks + GY
  hipMemsetAsync(ws, 0, (size_t)(WS_GY + GYS * GYS) * sizeof(float), stream);
  gram_kernel<<<NBX + NBY, 320, 0, stream>>>(x, y, mux, muy, Wz, Cz, P, n, ws);
  reduce_kernel<<<(PART_SZ + 255) / 256, 256, 0, stream>>>(ws);
  solve_kernel<<<1, 64, 0, stream>>>(ws, u, tss, bz, ws + WS_COEF, out);
  out_kernel<<<512 + 16, 256, 0, stream>>>(x, y, mux, muy, Wz, Cz, P, n, ws + WS_COEF, out);
}

// Round 3
// 320.568 us; speedup vs baseline: 1.1740x; 1.0702x over previous
//
#include <hip/hip_runtime.h>

// IPLS partial_fit (n > BURN_IN). Gram-reformulated:
//   x-side Gram 65x65 of [xc, P_0..31, Wz_0..31], y-side 33x33 of [yc, Cz_0..31]
//   -> 1-wave f64 scalar recurrence solve -> skinny 64x33 output combine.
// R3: x-side gram is ATOMIC-FREE (per-block partial slices + 2-stage tree
// reduce); out_kernel is 1-float/thread (B[33]=33 VGPRs, no spills).

#define NF 262144
#define NT 8192
#define NL 32
#define GXS 68
#define GYS 36
#define NBX 512          // x-side gram blocks (each: 2 windows of 256 floats)
#define NBY 32           // y-side gram blocks (1 window of 256)
#define NPAIR 66         // 11 groups of 6 rows -> 66 group-pairs
#define ENT (NPAIR*36)   // 2376 partial entries per block
#define NCH 32           // stage-1 reduce chunks
#define CHSZ (NBX/NCH)   // 16 slices per chunk

#define WS_PART  0
#define WS_PART2 (NBX*ENT)                   // 1216512
#define WS_GY    (WS_PART2 + NCH*ENT)        // 1292544
#define WS_GX    (WS_GY + GYS*GYS)           // 1293840
#define WS_COEF  (WS_GX + GXS*GXS)           // 1298464 (3*32*33 floats)

#define OUT_MU_X 0
#define OUT_MU_Y 262144
#define OUT_U    270336
#define OUT_WZ   270368
#define OUT_CZ   8658976
#define OUT_TSS  8921120
#define OUT_BZ   8921152
#define OUT_P    8921184

#define LDSW 260   // row stride (floats): 256 + 4 pad

__device__ __forceinline__ float4 ld4(const float* p) { return *(const float4*)p; }

__global__ __launch_bounds__(320) void gram_kernel(
    const float* __restrict__ x, const float* __restrict__ y,
    const float* __restrict__ mux, const float* __restrict__ muy,
    const float* __restrict__ Wz, const float* __restrict__ Cz,
    const float* __restrict__ P, const int* __restrict__ np,
    float* __restrict__ ws)
{
  __shared__ float lds[66 * LDSW];   // 68.6 KB -> 2 blocks/CU
  const int tid = threadIdx.x;
  const int b = blockIdx.x;
  const float n1 = (float)(np[0] + 1);
  const float cmu = n1 / (n1 + 1.0f);   // xc = cmu*(x - mu_old)

  if (b < NBX) {
    // ---- x-side: 66 rows (xc, P_0..31, Wz_0..31, zero), 6-row groups ----
    const int q = tid & 3;
    const int pidx = tid >> 2;
    int gu = 0, gv = 0; bool active = (tid < 264);
    if (active) {
      int pp = pidx;
      for (int g = 0; g < 11; ++g) {
        int c = 11 - g;
        if (pp < c) { gu = g; gv = g + pp; break; }
        pp -= c;
      }
    }
    float acc[36];
#pragma unroll
    for (int i = 0; i < 36; ++i) acc[i] = 0.f;

    for (int w = 0; w < 2; ++w) {
      const int wb = b * 512 + w * 256;
      for (int it = 0; it < 14; ++it) {
        int idx = tid + it * 320;
        if (idx < 4224) {
          int row = idx >> 6;
          int c4 = idx & 63;
          int k = wb + c4 * 4;
          float4 v;
          if (row == 0) {
            float4 xv = ld4(x + k), mv = ld4(mux + k);
            v.x = cmu * (xv.x - mv.x); v.y = cmu * (xv.y - mv.y);
            v.z = cmu * (xv.z - mv.z); v.w = cmu * (xv.w - mv.w);
          } else if (row < 33) {
            v = ld4(P + (size_t)(row - 1) * NF + k);
          } else if (row < 65) {
            v = ld4(Wz + (size_t)(row - 33) * NF + k);
          } else {
            v = make_float4(0.f, 0.f, 0.f, 0.f);
          }
          *(float4*)&lds[row * LDSW + c4 * 4] = v;
        }
      }
      __syncthreads();
      if (active) {
        const int ub = 6 * gu * LDSW, vb = 6 * gv * LDSW;
#pragma unroll 4
        for (int cc = 0; cc < 16; ++cc) {
          const int co = (q + cc * 4) * 4;
          float4 av[6], bv[6];
#pragma unroll
          for (int r = 0; r < 6; ++r) av[r] = *(const float4*)&lds[ub + r * LDSW + co];
#pragma unroll
          for (int s = 0; s < 6; ++s) bv[s] = *(const float4*)&lds[vb + s * LDSW + co];
#pragma unroll
          for (int r = 0; r < 6; ++r)
#pragma unroll
            for (int s = 0; s < 6; ++s)
              acc[r * 6 + s] += av[r].x * bv[s].x + av[r].y * bv[s].y +
                                av[r].z * bv[s].z + av[r].w * bv[s].w;
        }
      }
      __syncthreads();
    }
    // combine the 4 quarters (adjacent lanes within a wave)
#pragma unroll
    for (int e = 0; e < 36; ++e) {
      acc[e] += __shfl_xor(acc[e], 1, 64);
      acc[e] += __shfl_xor(acc[e], 2, 64);
    }
    if (active && q == 0) {
      // plain stores to this block's private partial slice
      float* PB = ws + WS_PART + (size_t)b * ENT + pidx * 36;
#pragma unroll
      for (int e4 = 0; e4 < 9; ++e4)
        *(float4*)&PB[e4 * 4] = make_float4(acc[e4 * 4], acc[e4 * 4 + 1],
                                            acc[e4 * 4 + 2], acc[e4 * 4 + 3]);
    }
  } else {
    // ---- y-side: 36 rows (yc, Cz_0..31, zeros), 4-row groups, 45 pairs ----
    float* GY = ws + WS_GY;
    const int yb = b - NBX;
    int gu = 0, gv = 0; bool active = (tid < 45);
    if (active) {
      int pp = tid;
      for (int g = 0; g < 9; ++g) {
        int c = 9 - g;
        if (pp < c) { gu = g; gv = g + pp; break; }
        pp -= c;
      }
    }
    float acc[16];
#pragma unroll
    for (int i = 0; i < 16; ++i) acc[i] = 0.f;
    const int wb = yb * 256;
    for (int it = 0; it < 8; ++it) {
      int idx = tid + it * 320;
      if (idx < 2304) {
        int row = idx >> 6;
        int c4 = idx & 63;
        int k = wb + c4 * 4;
        float4 v;
        if (row == 0) {
          float4 yv = ld4(y + k), mv = ld4(muy + k);
          v.x = cmu * (yv.x - mv.x); v.y = cmu * (yv.y - mv.y);
          v.z = cmu * (yv.z - mv.z); v.w = cmu * (yv.w - mv.w);
        } else if (row < 33) {
          v = ld4(Cz + (size_t)(row - 1) * NT + k);
        } else {
          v = make_float4(0.f, 0.f, 0.f, 0.f);
        }
        *(float4*)&lds[row * LDSW + c4 * 4] = v;
      }
    }
    __syncthreads();
    if (active) {
      const int ub = 4 * gu * LDSW, vb = 4 * gv * LDSW;
      for (int c = 0; c < 64; ++c) {
        float4 av[4], bv[4];
#pragma unroll
        for (int r = 0; r < 4; ++r) av[r] = *(const float4*)&lds[ub + r * LDSW + c * 4];
#pragma unroll
        for (int s = 0; s < 4; ++s) bv[s] = *(const float4*)&lds[vb + s * LDSW + c * 4];
#pragma unroll
        for (int r = 0; r < 4; ++r)
#pragma unroll
          for (int s = 0; s < 4; ++s)
            acc[r * 4 + s] += av[r].x * bv[s].x + av[r].y * bv[s].y +
                              av[r].z * bv[s].z + av[r].w * bv[s].w;
      }
#pragma unroll
      for (int r = 0; r < 4; ++r)
#pragma unroll
        for (int s = 0; s < 4; ++s) {
          int u = 4 * gu + r, v = 4 * gv + s;
          if (u < 33 && v < 33) {
            float val = acc[r * 4 + s];
            atomicAdd(&GY[u * GYS + v], val);
            if (gu != gv) atomicAdd(&GY[v * GYS + u], val);
          }
        }
    }
  }
}

// stage 1: 512 slices -> 32 chunk partials (coalesced)
__global__ __launch_bounds__(256) void reduce1_kernel(float* __restrict__ ws) {
  const int c = blockIdx.x / 10, eb = blockIdx.x % 10;
  const int e = eb * 256 + threadIdx.x;
  if (e < ENT) {
    const float* PB = ws + WS_PART + (size_t)c * CHSZ * ENT;
    float s = 0.f;
#pragma unroll
    for (int j = 0; j < CHSZ; ++j) s += PB[(size_t)j * ENT + e];
    ws[WS_PART2 + (size_t)c * ENT + e] = s;
  }
}

// stage 2: 32 chunk partials -> GX (scatter to 68x68 mirrored layout)
__global__ __launch_bounds__(256) void reduce2_kernel(float* __restrict__ ws) {
  const int e = blockIdx.x * 256 + threadIdx.x;
  if (e < ENT) {
    float s = 0.f;
#pragma unroll
    for (int c = 0; c < NCH; ++c) s += ws[WS_PART2 + (size_t)c * ENT + e];
    int p = e / 36, rs = e % 36;
    int gu = 0, gv = 0, pp = p;
    for (int g = 0; g < 11; ++g) {
      int cN = 11 - g;
      if (pp < cN) { gu = g; gv = g + pp; break; }
      pp -= cN;
    }
    int u = 6 * gu + rs / 6, v = 6 * gv + rs % 6;
    float* GX = ws + WS_GX;
    GX[u * GXS + v] = s;
    if (gu != gv) GX[v * GXS + u] = s;
  }
}

// One wave: f64 scalar recurrences for all 32 components.
__global__ void solve_kernel(const float* __restrict__ ws,
                             const float* __restrict__ u_in,
                             const float* __restrict__ tss_in,
                             const float* __restrict__ bz_in,
                             float* __restrict__ coef,
                             float* __restrict__ out)
{
  const int l = threadIdx.x;  // 0..63
  const float* GX = ws + WS_GX;
  const float* GY = ws + WS_GY;
  float* AWZ = coef;               // 32 x 33
  float* AP  = coef + 33 * NL;     // 32 x 33 (+P_i identity folded)
  float* ACZ = coef + 66 * NL;     // 32 x 33 (+Cz_i identity folded)

  double q = (double)GX[0];                       // ||xr||^2
  double r = (double)GY[0];                       // ||yr||^2
  double pj = (l < 32) ? (double)GX[1 + l]  : 0.0;
  double wj = (l < 32) ? (double)GX[33 + l] : 0.0;
  double ej = (l < 32) ? (double)GY[1 + l]  : 0.0;
  double cx = (l == 0) ? 1.0 : 0.0;
  double cy = (l == 0) ? 1.0 : 0.0;

  for (int i = 0; i < NL; ++i) {
    double a  = __shfl(wj, i, 64);
    double g  = __shfl(ej, i, 64);
    double pi = __shfl(pj, i, 64);
    double s  = (double)GX[(33 + i) * GXS + (33 + i)];
    double h  = (double)GY[(1 + i) * GYS + (1 + i)];
    double u0   = (double)u_in[i];
    double tss0 = (double)tss_in[i];
    double bz0  = (double)bz_in[i];

    double ui = u0, u1 = 0.0, tz = 0.0, tss_ = 0.0, t = 0.0, ncz = 1.0;
#pragma unroll
    for (int pass = 0; pass < 2; ++pass) {
      double num = a + ui * q;
      double den = sqrt(s + 2.0 * ui * a + ui * ui * q) + 1e-7;
      tz = num / den;
      tss_ = tss0 + tz * tz;
      t = tz / sqrt(tss_);
      double ncz2 = h + 2.0 * t * g + t * t * r;
      ncz = sqrt(ncz2);
      ui = (g + t * r) / ncz;
      if (pass == 0) u1 = ui;
    }
    double u2 = ui;
    double bz_new = bz0 + u2 * tz;
    double bb = bz_new / sqrt(tss_);
    double phi = 1.0 - t * t;            // xr' = phi*xr - t*P_i
    double gam = bb * t / ncz;           // yr' = psi*yr - gam*Cz_i
    double psi = 1.0 - gam * t;

    if (l == 0) {
      out[OUT_U + i]   = (float)u2;
      out[OUT_TSS + i] = (float)tss_;
      out[OUT_BZ + i]  = (float)bz_new;
    }
    if (l < 33) {
      AWZ[i * 33 + l] = (float)(u1 * cx);
      AP [i * 33 + l] = (float)(t  * cx) + ((l == 1 + i) ? 1.0f : 0.0f);
      ACZ[i * 33 + l] = (float)(t  * cy) + ((l == 1 + i) ? 1.0f : 0.0f);
    }
    q = phi * phi * q - 2.0 * phi * t * pi + t * t * (double)GX[(1 + i) * GXS + (1 + i)];
    r = psi * psi * r - 2.0 * psi * gam * g + gam * gam * h;
    cx *= phi; if (l == 1 + i) cx -= t;
    cy *= psi; if (l == 1 + i) cy -= gam;
    if (l < 32) {
      pj = phi * pj - t * (double)GX[(1 + i) * GXS + (1 + l)];
      wj = phi * wj - t * (double)GX[(1 + i) * GXS + (33 + l)];
      ej = psi * ej - gam * (double)GY[(1 + i) * GYS + (1 + l)];
    }
  }
}

// 1 float/thread: B[33] = 33 VGPRs, no spills; 1056 blocks -> ~16 waves/CU.
__global__ __launch_bounds__(256) void out_kernel(
    const float* __restrict__ x, const float* __restrict__ y,
    const float* __restrict__ mux, const float* __restrict__ muy,
    const float* __restrict__ Wz, const float* __restrict__ Cz,
    const float* __restrict__ P, const int* __restrict__ np,
    const float* __restrict__ coef, float* __restrict__ out)
{
  const int b = blockIdx.x, tid = threadIdx.x;
  const float n1 = (float)(np[0] + 1);
  const float inv = 1.0f / (n1 + 1.0f);
  const float* AWZ = coef;
  const float* AP  = coef + 33 * NL;
  const float* ACZ = coef + 66 * NL;

  if (b < 1024) {
    const int k = b * 256 + tid;
    float xv = x[k], mv = mux[k];
    float mn = (mv * n1 + xv) * inv;
    out[OUT_MU_X + k] = mn;
    float B[33];
    B[0] = xv - mn;
#pragma unroll
    for (int j = 0; j < 32; ++j) B[1 + j] = P[(size_t)j * NF + k];
    for (int i = 0; i < NL; ++i) {
      float aw = Wz[(size_t)i * NF + k];
      float ap = 0.f;
#pragma unroll
      for (int j = 0; j < 33; ++j) {
        aw += AWZ[i * 33 + j] * B[j];
        ap += AP[i * 33 + j] * B[j];
      }
      out[OUT_WZ + (size_t)i * NF + k] = aw;
      out[OUT_P  + (size_t)i * NF + k] = ap;
    }
  } else {
    const int k = (b - 1024) * 256 + tid;
    float yv = y[k], mv = muy[k];
    float mn = (mv * n1 + yv) * inv;
    out[OUT_MU_Y + k] = mn;
    float B[33];
    B[0] = yv - mn;
#pragma unroll
    for (int j = 0; j < 32; ++j) B[1 + j] = Cz[(size_t)j * NT + k];
    for (int i = 0; i < NL; ++i) {
      float ac = 0.f;
#pragma unroll
      for (int j = 0; j < 33; ++j) ac += ACZ[i * 33 + j] * B[j];
      out[OUT_CZ + (size_t)i * NT + k] = ac;
    }
  }
}

extern "C" void kernel_launch(void* const* d_in, const int* in_sizes, int n_in,
                              void* d_out, int out_size, void* d_ws, size_t ws_size,
                              hipStream_t stream) {
  const float* x   = (const float*)d_in[0];
  const float* y   = (const float*)d_in[1];
  const float* mux = (const float*)d_in[2];
  const float* muy = (const float*)d_in[3];
  const float* u   = (const float*)d_in[4];
  const float* Wz  = (const float*)d_in[5];
  const float* Cz  = (const float*)d_in[6];
  const float* tss = (const float*)d_in[7];
  const float* bz  = (const float*)d_in[8];
  const float* P   = (const float*)d_in[9];
  const int*   n   = (const int*)d_in[10];
  float* ws  = (float*)d_ws;
  float* out = (float*)d_out;

  // only GY is atomically accumulated -> zero just that region
  hipMemsetAsync(ws + WS_GY, 0, (size_t)(GYS * GYS) * sizeof(float), stream);
  gram_kernel<<<NBX + NBY, 320, 0, stream>>>(x, y, mux, muy, Wz, Cz, P, n, ws);
  reduce1_kernel<<<NCH * 10, 256, 0, stream>>>(ws);
  reduce2_kernel<<<10, 256, 0, stream>>>(ws);
  solve_kernel<<<1, 64, 0, stream>>>(ws, u, tss, bz, ws + WS_COEF, out);
  out_kernel<<<1024 + 32, 256, 0, stream>>>(x, y, mux, muy, Wz, Cz, P, n, ws + WS_COEF, out);
}